// Round 3
// baseline (1290.826 us; speedup 1.0000x reference)
//
#include <hip/hip_runtime.h>

#define TTOK 4096
#define DDIM 1024
#define HDIM 4096
#define NEXP 64
#define CAP  512
#define NASN (TTOK*3)

typedef unsigned short u16;
typedef __attribute__((ext_vector_type(8))) short s16x8;
typedef __attribute__((ext_vector_type(4))) short s16x4;
typedef __attribute__((ext_vector_type(4))) float f32x4;

__device__ __forceinline__ u16 f2bf(float f) {
  union { float f; unsigned u; } v; v.f = f;
  unsigned u = v.u;
  return (u16)((u + 0x7fffu + ((u >> 16) & 1u)) >> 16);
}

// ---------------- fast zero for the output (atomicAdd target) ----------------
__global__ __launch_bounds__(256) void zero_out(float4* __restrict__ p, int n4) {
  int i = blockIdx.x * 256 + threadIdx.x;
  int st = gridDim.x * 256;
  for (; i < n4; i += st) p[i] = (float4){0.f, 0.f, 0.f, 0.f};
}

// ---------------- gating: logits + top-3 + softmax ----------------
__global__ __launch_bounds__(512) void gate_topk(
    const float* __restrict__ x, const float* __restrict__ gw,
    const float* __restrict__ gb, int* __restrict__ fe, float* __restrict__ fg)
{
  int lane = threadIdx.x & 63;
  int wid  = threadIdx.x >> 6;
  int t = blockIdx.x * 8 + wid;
  const float* xr = x + (size_t)t * DDIM;
  float acc = gb[lane];
  #pragma unroll 4
  for (int d = 0; d < DDIM; d++) acc += xr[d] * gw[d * NEXP + lane];

  float v = acc;
  float bv[3]; int bi[3];
  #pragma unroll
  for (int j = 0; j < 3; j++) {
    float mv = v; int mi = lane;
    #pragma unroll
    for (int off = 32; off; off >>= 1) {
      float ov = __shfl_xor(mv, off);
      int   oi = __shfl_xor(mi, off);
      if (ov > mv || (ov == mv && oi < mi)) { mv = ov; mi = oi; }
    }
    bv[j] = mv; bi[j] = mi;
    if (lane == mi) v = -3.4e38f;
  }
  if (lane == 0) {
    float e1 = expf(bv[1] - bv[0]), e2 = expf(bv[2] - bv[0]);
    float inv = 1.0f / (1.0f + e1 + e2);
    fe[t*3+0] = bi[0]; fe[t*3+1] = bi[1]; fe[t*3+2] = bi[2];
    fg[t*3+0] = inv;   fg[t*3+1] = e1*inv; fg[t*3+2] = e2*inv;
  }
}

// ------- order-preserving per-expert slot assignment (exact ref semantics) -------
__global__ __launch_bounds__(64) void scan_pos(
    const int* __restrict__ fe, int* __restrict__ posA,
    int* __restrict__ s2a, int* __restrict__ cnt)
{
  int e = blockIdx.x, lane = threadIdx.x;
  int base = 0;
  for (int i0 = 0; i0 < NASN; i0 += 64) {
    int i = i0 + lane;
    bool m = (fe[i] == e);
    unsigned long long bal = __ballot(m);
    int below = __popcll(bal & ((1ull << lane) - 1ull));
    if (m) {
      int p = base + below;
      posA[i] = p;
      if (p < CAP) s2a[e * CAP + p] = i;
    }
    base += __popcll(bal);
  }
  if (lane == 0) cnt[e] = base < CAP ? base : CAP;
}

// ---------------- dispatch: scatter x rows into bf16 expert buffers ----------------
__global__ __launch_bounds__(64) void dispatch(
    const float* __restrict__ x, const int* __restrict__ fe,
    const int* __restrict__ posA, u16* __restrict__ bufA)
{
  int a = blockIdx.x;
  int p = posA[a];
  if (p >= CAP) return;
  int e = fe[a];
  int tok = a / 3;
  int l = threadIdx.x;
  const float4* xr = (const float4*)(x + (size_t)tok * DDIM);
  u16* dst = bufA + ((size_t)e * CAP + p) * DDIM;
  #pragma unroll
  for (int j = 0; j < 4; j++) {
    float4 v = xr[j * 64 + l];
    uint2 u;
    u.x = (unsigned)f2bf(v.x) | ((unsigned)f2bf(v.y) << 16);
    u.y = (unsigned)f2bf(v.z) | ((unsigned)f2bf(v.w) << 16);
    *(uint2*)(dst + (size_t)(j * 64 + l) * 4) = u;
  }
}

// =================== expert GEMM v2: reg-direct A, pipelined B ===================
// BM=256, BN=64, BK=64, 4 waves. A fragments load global->VGPR (L2-hot, no LDS).
// B (fp32 weights): 2-tile-deep register prefetch + LDS double buffer.
// Raw s_barrier + lgkmcnt(0) only -- no vmcnt drain, loads stay in flight.
// EPI==1: h = gelu(A*W1 + b1) -> bf16   EPI==2: atomic gated combine of A*W2 + b2
#define BSTRIDE 136
#define BBYTES  (64 * BSTRIDE)

template<int KTOT, int NTOT, int EPI>
__global__ __launch_bounds__(256, 2) void moe_gemm(
    const u16* __restrict__ Abuf, const float* __restrict__ W,
    const float* __restrict__ bias, u16* __restrict__ hout,
    float* __restrict__ out, const int* __restrict__ cnt,
    const int* __restrict__ s2a, const float* __restrict__ fg, int g0)
{
  constexpr int NCT = NTOT / 64;
  constexpr int NT  = KTOT / 64;
  int NB = gridDim.x;
  int b = blockIdx.x;
  int L = (b & 7) * (NB >> 3) + (b >> 3);   // XCD-bijective swizzle (NB % 8 == 0)
  int tcol = L % NCT;
  int rt   = (L / NCT) & 1;
  int el   = L / (NCT * 2);
  int e    = g0 + el;
  int cnte = cnt[e];
  int c0   = rt * 256;
  if (c0 >= cnte) return;
  int n0 = tcol * 64;

  int tid = threadIdx.x, l = tid & 63, w = tid >> 6;

  __shared__ char Bs[2 * BBYTES];   // [buf][64 n][64+4 bf16] K-major

  const u16* Arows = Abuf + ((size_t)((EPI == 1 ? e : el)) * CAP + c0) * (size_t)KTOT;
  const float* We = W + (size_t)e * KTOT * NTOT + n0;

  // per-thread B staging geometry: n = l, k-group = w (16 k each)
  const float* Wt = We + l + (size_t)(w * 16) * NTOT;
  char* BsW = Bs + l * BSTRIDE + w * 32;

  float br0[16], br1[16];
  #define LOADB(dst, t) { \
    const float* p_ = Wt + (size_t)(t) * 64 * NTOT; \
    _Pragma("unroll") \
    for (int j_ = 0; j_ < 4; j_++) { \
      _Pragma("unroll") \
      for (int r_ = 0; r_ < 4; r_++) \
        dst[j_ * 4 + r_] = p_[(size_t)(j_ * 4 + r_) * NTOT]; \
    } }
  #define STOREB(src, buf) { \
    char* q_ = BsW + (buf) * BBYTES; \
    _Pragma("unroll") \
    for (int j_ = 0; j_ < 4; j_++) { \
      uint2 u_; \
      u_.x = (unsigned)f2bf(src[j_*4+0]) | ((unsigned)f2bf(src[j_*4+1]) << 16); \
      u_.y = (unsigned)f2bf(src[j_*4+2]) | ((unsigned)f2bf(src[j_*4+3]) << 16); \
      *(uint2*)(q_ + j_ * 8) = u_; \
    } }
  #define BARRIER() { asm volatile("s_waitcnt lgkmcnt(0)" ::: "memory"); \
                      __builtin_amdgcn_s_barrier(); }

  // A fragment addresses: lane l holds A[row=base+(l&15)][k=(l>>4)*8 + j]
  const u16* Abase = Arows + (size_t)(w * 64 + (l & 15)) * KTOT + (l >> 4) * 8;

  #define LOADA(t) \
    _Pragma("unroll") \
    for (int m_ = 0; m_ < 4; m_++) { \
      _Pragma("unroll") \
      for (int k2_ = 0; k2_ < 2; k2_++) \
        af[m_][k2_] = *(const s16x8*)(Abase + (size_t)(m_ * 16) * KTOT + (t) * 64 + k2_ * 32); \
    }

  #define READB(buf) \
    _Pragma("unroll") \
    for (int nn_ = 0; nn_ < 4; nn_++) { \
      _Pragma("unroll") \
      for (int k2_ = 0; k2_ < 2; k2_++) { \
        const char* bp_ = Bs + (buf) * BBYTES + (nn_ * 16 + (l & 15)) * BSTRIDE \
                          + (k2_ * 32 + (l >> 4) * 8) * 2; \
        union { s16x8 v8; s16x4 v4[2]; } bu_; \
        bu_.v4[0] = *(const s16x4*)bp_; \
        bu_.v4[1] = *(const s16x4*)(bp_ + 8); \
        bf[nn_][k2_] = bu_.v8; \
      } }

  #define MFMA16() \
    _Pragma("unroll") \
    for (int k2_ = 0; k2_ < 2; k2_++) \
      _Pragma("unroll") \
      for (int m_ = 0; m_ < 4; m_++) \
        _Pragma("unroll") \
        for (int nn_ = 0; nn_ < 4; nn_++) \
          acc[m_][nn_] = __builtin_amdgcn_mfma_f32_16x16x32_bf16(af[m_][k2_], bf[nn_][k2_], acc[m_][nn_], 0, 0, 0);

  f32x4 acc[4][4];
  #pragma unroll
  for (int m = 0; m < 4; m++)
    #pragma unroll
    for (int nn = 0; nn < 4; nn++)
      acc[m][nn] = (f32x4){0.f, 0.f, 0.f, 0.f};

  s16x8 af[4][2], bf[4][2];

  // prologue: B tiles 0,1 -> regs; stage Bs[0]
  LOADB(br0, 0);
  LOADB(br1, 1);
  STOREB(br0, 0);
  BARRIER();

  for (int t = 0; t < NT; t += 2) {
    // even: compute tile t from Bs[0]; stage Bs[1]<-br1(t+1); refill br0<-t+2
    LOADA(t);
    STOREB(br1, 1);
    if (t + 2 < NT) LOADB(br0, t + 2);
    READB(0);
    MFMA16();
    BARRIER();
    // odd: compute tile t+1 from Bs[1]; stage Bs[0]<-br0(t+2); refill br1<-t+3
    LOADA(t + 1);
    if (t + 2 < NT) { STOREB(br0, 0); }
    if (t + 3 < NT) LOADB(br1, t + 3);
    READB(1);
    MFMA16();
    BARRIER();
  }

  int lr = l >> 4, lc = l & 15;
  float bv[4];
  #pragma unroll
  for (int nn = 0; nn < 4; nn++) bv[nn] = bias[(size_t)e * NTOT + n0 + nn * 16 + lc];

  if (EPI == 1) {
    #pragma unroll
    for (int m = 0; m < 4; m++)
      #pragma unroll
      for (int nn = 0; nn < 4; nn++)
        #pragma unroll
        for (int q = 0; q < 4; q++) {
          int rowL = w * 64 + m * 16 + lr * 4 + q;
          float vv = acc[m][nn][q] + bv[nn];
          vv = 0.5f * vv * (1.0f + erff(vv * 0.70710678118f));
          hout[(size_t)(el * CAP + c0 + rowL) * NTOT + (n0 + nn * 16 + lc)] = f2bf(vv);
        }
  } else {
    #pragma unroll
    for (int m = 0; m < 4; m++) {
      int rowbase = w * 64 + m * 16 + lr * 4;
      #pragma unroll
      for (int q = 0; q < 4; q++) {
        int slot = c0 + rowbase + q;
        if (slot < cnte) {
          int aidx = s2a[e * CAP + slot];
          int tok = aidx / 3;
          float gg = fg[aidx];
          #pragma unroll
          for (int nn = 0; nn < 4; nn++) {
            float vv = (acc[m][nn][q] + bv[nn]) * gg;
            atomicAdd(out + (size_t)tok * DDIM + (n0 + nn * 16 + lc), vv);
          }
        }
      }
    }
  }
}

extern "C" void kernel_launch(void* const* d_in, const int* in_sizes, int n_in,
                              void* d_out, int out_size, void* d_ws, size_t ws_size,
                              hipStream_t stream) {
  (void)in_sizes; (void)n_in;
  const float* x  = (const float*)d_in[0];
  const float* gw = (const float*)d_in[1];
  const float* gb = (const float*)d_in[2];
  const float* w1 = (const float*)d_in[3];
  const float* b1 = (const float*)d_in[4];
  const float* w2 = (const float*)d_in[5];
  const float* b2 = (const float*)d_in[6];
  float* out = (float*)d_out;

  char* ws = (char*)d_ws;
  int*   fe   = (int*)(ws);
  float* fg   = (float*)(ws + 49152);
  int*   posA = (int*)(ws + 98304);
  int*   s2a  = (int*)(ws + 147456);
  int*   cnt  = (int*)(ws + 278528);
  u16*   bufA = (u16*)(ws + (1 << 20));
  u16*   hbuf = (u16*)(ws + (1 << 20) + 67108864ull);

  size_t fixed = (1 << 20) + 67108864ull;
  int GE = 16;   // experts per group: hbuf = 64MB -> L3-resident between GEMM1/GEMM2
  while (GE > 1 && fixed + (size_t)GE * CAP * HDIM * 2 > ws_size) GE >>= 1;

  zero_out<<<1024, 256, 0, stream>>>((float4*)out, out_size / 4);
  gate_topk<<<TTOK / 8, 512, 0, stream>>>(x, gw, gb, fe, fg);
  scan_pos<<<NEXP, 64, 0, stream>>>(fe, posA, s2a, cnt);
  dispatch<<<NASN, 64, 0, stream>>>(x, fe, posA, bufA);

  for (int g0 = 0; g0 < NEXP; g0 += GE) {
    moe_gemm<DDIM, HDIM, 1><<<GE * 2 * (HDIM / 64), 256, 0, stream>>>(
        bufA, w1, b1, hbuf, nullptr, cnt, nullptr, nullptr, g0);
    moe_gemm<HDIM, DDIM, 2><<<GE * 2 * (DDIM / 64), 256, 0, stream>>>(
        hbuf, w2, b2, nullptr, out, cnt, s2a, fg, g0);
  }
}

// Round 4
// 758.496 us; speedup vs baseline: 1.7018x; 1.7018x over previous
//
#include <hip/hip_runtime.h>

#define TTOK 4096
#define DDIM 1024
#define HDIM 4096
#define NEXP 64
#define CAP  512
#define NASN (TTOK*3)

typedef unsigned short u16;
typedef __attribute__((ext_vector_type(8))) short s16x8;
typedef __attribute__((ext_vector_type(4))) short s16x4;
typedef __attribute__((ext_vector_type(4))) float f32x4;

__device__ __forceinline__ u16 f2bf(float f) {
  union { float f; unsigned u; } v; v.f = f;
  unsigned u = v.u;
  return (u16)((u + 0x7fffu + ((u >> 16) & 1u)) >> 16);
}

__device__ __forceinline__ void gl_lds16(const void* g, void* l) {
  __builtin_amdgcn_global_load_lds(
      (const __attribute__((address_space(1))) void*)g,
      (__attribute__((address_space(3))) void*)l, 16, 0, 0);
}

// ---------------- fast zero for the output (atomicAdd target) ----------------
__global__ __launch_bounds__(256) void zero_out(float4* __restrict__ p, int n4) {
  int i = blockIdx.x * 256 + threadIdx.x;
  int st = gridDim.x * 256;
  for (; i < n4; i += st) p[i] = (float4){0.f, 0.f, 0.f, 0.f};
}

// ---------------- gating: logits + top-3 + softmax ----------------
__global__ __launch_bounds__(512) void gate_topk(
    const float* __restrict__ x, const float* __restrict__ gw,
    const float* __restrict__ gb, int* __restrict__ fe, float* __restrict__ fg)
{
  int lane = threadIdx.x & 63;
  int wid  = threadIdx.x >> 6;
  int t = blockIdx.x * 8 + wid;
  const float* xr = x + (size_t)t * DDIM;
  float acc = gb[lane];
  #pragma unroll 4
  for (int d = 0; d < DDIM; d++) acc += xr[d] * gw[d * NEXP + lane];

  float v = acc;
  float bv[3]; int bi[3];
  #pragma unroll
  for (int j = 0; j < 3; j++) {
    float mv = v; int mi = lane;
    #pragma unroll
    for (int off = 32; off; off >>= 1) {
      float ov = __shfl_xor(mv, off);
      int   oi = __shfl_xor(mi, off);
      if (ov > mv || (ov == mv && oi < mi)) { mv = ov; mi = oi; }
    }
    bv[j] = mv; bi[j] = mi;
    if (lane == mi) v = -3.4e38f;
  }
  if (lane == 0) {
    float e1 = expf(bv[1] - bv[0]), e2 = expf(bv[2] - bv[0]);
    float inv = 1.0f / (1.0f + e1 + e2);
    fe[t*3+0] = bi[0]; fe[t*3+1] = bi[1]; fe[t*3+2] = bi[2];
    fg[t*3+0] = inv;   fg[t*3+1] = e1*inv; fg[t*3+2] = e2*inv;
  }
}

// ------- order-preserving per-expert slot assignment (exact ref semantics) -------
__global__ __launch_bounds__(64) void scan_pos(
    const int* __restrict__ fe, int* __restrict__ posA,
    int* __restrict__ s2a, int* __restrict__ cnt)
{
  int e = blockIdx.x, lane = threadIdx.x;
  int base = 0;
  for (int i0 = 0; i0 < NASN; i0 += 64) {
    int i = i0 + lane;
    bool m = (fe[i] == e);
    unsigned long long bal = __ballot(m);
    int below = __popcll(bal & ((1ull << lane) - 1ull));
    if (m) {
      int p = base + below;
      posA[i] = p;
      if (p < CAP) s2a[e * CAP + p] = i;
    }
    base += __popcll(bal);
  }
  if (lane == 0) cnt[e] = base < CAP ? base : CAP;
}

// ---------------- dispatch: scatter x rows into bf16 expert buffers ----------------
__global__ __launch_bounds__(64) void dispatch(
    const float* __restrict__ x, const int* __restrict__ fe,
    const int* __restrict__ posA, u16* __restrict__ bufA)
{
  int a = blockIdx.x;
  int p = posA[a];
  if (p >= CAP) return;
  int e = fe[a];
  int tok = a / 3;
  int l = threadIdx.x;
  const float4* xr = (const float4*)(x + (size_t)tok * DDIM);
  u16* dst = bufA + ((size_t)e * CAP + p) * DDIM;
  #pragma unroll
  for (int j = 0; j < 4; j++) {
    float4 v = xr[j * 64 + l];
    uint2 u;
    u.x = (unsigned)f2bf(v.x) | ((unsigned)f2bf(v.y) << 16);
    u.y = (unsigned)f2bf(v.z) | ((unsigned)f2bf(v.w) << 16);
    *(uint2*)(dst + (size_t)(j * 64 + l) * 4) = u;
  }
}

// ---------------- expert GEMM: BM=256, BN=128, BK=64, 4 waves ----------------
// v1 structure (coalesced global_load_lds A + LDS-transposed B), widened to BN=128.
// EPI==1: h = gelu(A*W1 + b1) -> bf16   EPI==2: atomic gated combine of A*W2 + b2
// A-tile pad rows (>= cnt[e]) hold stale finite bytes; all influenced outputs are
// discarded (slot<cnte gate / h rows ignored), so no zero-fill needed.
template<int KTOT, int NTOT, int EPI>
__global__ __launch_bounds__(256, 2) void moe_gemm(
    const u16* __restrict__ Abuf, const float* __restrict__ W,
    const float* __restrict__ bias, u16* __restrict__ hout,
    float* __restrict__ out, const int* __restrict__ cnt,
    const int* __restrict__ s2a, const float* __restrict__ fg, int g0)
{
  constexpr int NCT = NTOT / 128;
  int NB = gridDim.x;
  int b = blockIdx.x;
  int L = (b & 7) * (NB >> 3) + (b >> 3);   // XCD-bijective swizzle (NB % 8 == 0)
  int tcol = L % NCT;
  int rt   = (L / NCT) & 1;
  int el   = L / (NCT * 2);
  int e    = g0 + el;
  int cnte = cnt[e];
  int c0   = rt * 256;
  if (c0 >= cnte) return;
  int n0 = tcol * 128;

  int tid = threadIdx.x, l = tid & 63, w = tid >> 6;

  __shared__ char AsB[256 * 128];   // [256 rows][64 bf16] chunk-swizzled
  __shared__ char BsB[128 * 136];   // [128 n][64+4 bf16] K-major transposed

  const u16* Arows = Abuf + ((size_t)((EPI == 1 ? e : el)) * CAP + c0) * (size_t)KTOT;
  const float* We = W + (size_t)e * KTOT * NTOT;

  f32x4 acc[4][8];
  #pragma unroll
  for (int m = 0; m < 4; m++)
    #pragma unroll
    for (int nn = 0; nn < 8; nn++)
      acc[m][nn] = (f32x4){0.f, 0.f, 0.f, 0.f};

  for (int k0 = 0; k0 < KTOT; k0 += 64) {
    // A tile: 8 async issues, 16B/lane; source chunk pre-swizzled (XOR row&7)
    #pragma unroll
    for (int i = 0; i < 8; i++) {
      int r = i * 32 + w * 8 + (l >> 3);
      int cswz = (l & 7) ^ (r & 7);
      const char* gsrc = (const char*)(Arows + (size_t)r * KTOT + k0) + cswz * 16;
      char* ldst = AsB + (i * 32 + w * 8) * 128;
      gl_lds16(gsrc, ldst);
    }
    // B tile (64k x 128n fp32): lane-coalesced dword loads, convert, K-major store
    {
      int n = tid & 127, kg = tid >> 7;          // kg in {0,1}: 32 k each
      #pragma unroll
      for (int j = 0; j < 8; j++) {
        int k = kg * 32 + j * 4;
        const float* p = We + (size_t)(k0 + k) * NTOT + (n0 + n);
        float v0 = p[0], v1 = p[NTOT], v2 = p[2 * NTOT], v3 = p[3 * NTOT];
        uint2 u;
        u.x = (unsigned)f2bf(v0) | ((unsigned)f2bf(v1) << 16);
        u.y = (unsigned)f2bf(v2) | ((unsigned)f2bf(v3) << 16);
        *(uint2*)(BsB + n * 136 + k * 2) = u;
      }
    }
    __syncthreads();
    #pragma unroll
    for (int k2 = 0; k2 < 2; k2++) {
      int kb = k2 * 32;
      s16x8 af[4], bf8[8];
      #pragma unroll
      for (int m = 0; m < 4; m++) {
        int R = w * 64 + m * 16 + (l & 15);
        int chunk = (kb >> 3) + (l >> 4);
        int sc = chunk ^ (R & 7);
        af[m] = *(const s16x8*)(AsB + R * 128 + sc * 16);
      }
      #pragma unroll
      for (int nn = 0; nn < 8; nn++) {
        int Nn = nn * 16 + (l & 15);
        int kk = kb + (l >> 4) * 8;
        const char* bp = BsB + Nn * 136 + kk * 2;
        union { s16x8 v8; s16x4 v4[2]; } bu;
        bu.v4[0] = *(const s16x4*)bp;
        bu.v4[1] = *(const s16x4*)(bp + 8);
        bf8[nn] = bu.v8;
      }
      #pragma unroll
      for (int m = 0; m < 4; m++)
        #pragma unroll
        for (int nn = 0; nn < 8; nn++)
          acc[m][nn] = __builtin_amdgcn_mfma_f32_16x16x32_bf16(af[m], bf8[nn], acc[m][nn], 0, 0, 0);
    }
    __syncthreads();
  }

  int lr = l >> 4, lc = l & 15;
  float bv[8];
  #pragma unroll
  for (int nn = 0; nn < 8; nn++) bv[nn] = bias[(size_t)e * NTOT + n0 + nn * 16 + lc];

  if (EPI == 1) {
    #pragma unroll
    for (int m = 0; m < 4; m++)
      #pragma unroll
      for (int nn = 0; nn < 8; nn++)
        #pragma unroll
        for (int q = 0; q < 4; q++) {
          int rowL = w * 64 + m * 16 + lr * 4 + q;
          float vv = acc[m][nn][q] + bv[nn];
          vv = 0.5f * vv * (1.0f + erff(vv * 0.70710678118f));
          hout[(size_t)(el * CAP + c0 + rowL) * NTOT + (n0 + nn * 16 + lc)] = f2bf(vv);
        }
  } else {
    #pragma unroll
    for (int m = 0; m < 4; m++) {
      int rowbase = w * 64 + m * 16 + lr * 4;
      #pragma unroll
      for (int q = 0; q < 4; q++) {
        int slot = c0 + rowbase + q;
        if (slot < cnte) {
          int aidx = s2a[e * CAP + slot];
          int tok = aidx / 3;
          float gg = fg[aidx];
          #pragma unroll
          for (int nn = 0; nn < 8; nn++) {
            float vv = (acc[m][nn][q] + bv[nn]) * gg;
            atomicAdd(out + (size_t)tok * DDIM + (n0 + nn * 16 + lc), vv);
          }
        }
      }
    }
  }
}

extern "C" void kernel_launch(void* const* d_in, const int* in_sizes, int n_in,
                              void* d_out, int out_size, void* d_ws, size_t ws_size,
                              hipStream_t stream) {
  (void)in_sizes; (void)n_in; (void)ws_size;
  const float* x  = (const float*)d_in[0];
  const float* gw = (const float*)d_in[1];
  const float* gb = (const float*)d_in[2];
  const float* w1 = (const float*)d_in[3];
  const float* b1 = (const float*)d_in[4];
  const float* w2 = (const float*)d_in[5];
  const float* b2 = (const float*)d_in[6];
  float* out = (float*)d_out;

  char* ws = (char*)d_ws;
  int*   fe   = (int*)(ws);
  float* fg   = (float*)(ws + 49152);
  int*   posA = (int*)(ws + 98304);
  int*   s2a  = (int*)(ws + 147456);
  int*   cnt  = (int*)(ws + 278528);
  u16*   bufA = (u16*)(ws + (1 << 20));
  u16*   hbuf = (u16*)(ws + (1 << 20) + 67108864ull);

  zero_out<<<1024, 256, 0, stream>>>((float4*)out, out_size / 4);
  gate_topk<<<TTOK / 8, 512, 0, stream>>>(x, gw, gb, fe, fg);
  scan_pos<<<NEXP, 64, 0, stream>>>(fe, posA, s2a, cnt);
  dispatch<<<NASN, 64, 0, stream>>>(x, fe, posA, bufA);

  moe_gemm<DDIM, HDIM, 1><<<NEXP * 2 * (HDIM / 128), 256, 0, stream>>>(
      bufA, w1, b1, hbuf, nullptr, cnt, nullptr, nullptr, 0);
  moe_gemm<HDIM, DDIM, 2><<<NEXP * 2 * (DDIM / 128), 256, 0, stream>>>(
      hbuf, w2, b2, nullptr, out, cnt, s2a, fg, 0);
}

// Round 5
// 742.391 us; speedup vs baseline: 1.7387x; 1.0217x over previous
//
#include <hip/hip_runtime.h>

#define TTOK 4096
#define DDIM 1024
#define HDIM 4096
#define NEXP 64
#define CAP  512
#define NASN (TTOK*3)

typedef unsigned short u16;
typedef __attribute__((ext_vector_type(8))) short s16x8;
typedef __attribute__((ext_vector_type(4))) short s16x4;
typedef __attribute__((ext_vector_type(4))) float f32x4;

__device__ __forceinline__ u16 f2bf(float f) {
  union { float f; unsigned u; } v; v.f = f;
  unsigned u = v.u;
  return (u16)((u + 0x7fffu + ((u >> 16) & 1u)) >> 16);
}

__device__ __forceinline__ void gl_lds16(const void* g, void* l) {
  __builtin_amdgcn_global_load_lds(
      (const __attribute__((address_space(1))) void*)g,
      (__attribute__((address_space(3))) void*)l, 16, 0, 0);
}

// ---------------- fast zero for the output (atomicAdd target) ----------------
__global__ __launch_bounds__(256) void zero_out(float4* __restrict__ p, int n4) {
  int i = blockIdx.x * 256 + threadIdx.x;
  int st = gridDim.x * 256;
  for (; i < n4; i += st) p[i] = (float4){0.f, 0.f, 0.f, 0.f};
}

// ---------------- gating: logits + top-3 + softmax ----------------
__global__ __launch_bounds__(512) void gate_topk(
    const float* __restrict__ x, const float* __restrict__ gw,
    const float* __restrict__ gb, int* __restrict__ fe, float* __restrict__ fg)
{
  int lane = threadIdx.x & 63;
  int wid  = threadIdx.x >> 6;
  int t = blockIdx.x * 8 + wid;
  const float* xr = x + (size_t)t * DDIM;
  float acc = gb[lane];
  #pragma unroll 4
  for (int d = 0; d < DDIM; d++) acc += xr[d] * gw[d * NEXP + lane];

  float v = acc;
  float bv[3]; int bi[3];
  #pragma unroll
  for (int j = 0; j < 3; j++) {
    float mv = v; int mi = lane;
    #pragma unroll
    for (int off = 32; off; off >>= 1) {
      float ov = __shfl_xor(mv, off);
      int   oi = __shfl_xor(mi, off);
      if (ov > mv || (ov == mv && oi < mi)) { mv = ov; mi = oi; }
    }
    bv[j] = mv; bi[j] = mi;
    if (lane == mi) v = -3.4e38f;
  }
  if (lane == 0) {
    float e1 = expf(bv[1] - bv[0]), e2 = expf(bv[2] - bv[0]);
    float inv = 1.0f / (1.0f + e1 + e2);
    fe[t*3+0] = bi[0]; fe[t*3+1] = bi[1]; fe[t*3+2] = bi[2];
    fg[t*3+0] = inv;   fg[t*3+1] = e1*inv; fg[t*3+2] = e2*inv;
  }
}

// ------- order-preserving per-expert slot assignment (exact ref semantics) -------
__global__ __launch_bounds__(64) void scan_pos(
    const int* __restrict__ fe, int* __restrict__ posA,
    int* __restrict__ s2a, int* __restrict__ cnt)
{
  int e = blockIdx.x, lane = threadIdx.x;
  int base = 0;
  for (int i0 = 0; i0 < NASN; i0 += 64) {
    int i = i0 + lane;
    bool m = (fe[i] == e);
    unsigned long long bal = __ballot(m);
    int below = __popcll(bal & ((1ull << lane) - 1ull));
    if (m) {
      int p = base + below;
      posA[i] = p;
      if (p < CAP) s2a[e * CAP + p] = i;
    }
    base += __popcll(bal);
  }
  if (lane == 0) cnt[e] = base < CAP ? base : CAP;
}

// ---------------- dispatch: scatter x rows into bf16 expert buffers ----------------
__global__ __launch_bounds__(64) void dispatch(
    const float* __restrict__ x, const int* __restrict__ fe,
    const int* __restrict__ posA, u16* __restrict__ bufA)
{
  int a = blockIdx.x;
  int p = posA[a];
  if (p >= CAP) return;
  int e = fe[a];
  int tok = a / 3;
  int l = threadIdx.x;
  const float4* xr = (const float4*)(x + (size_t)tok * DDIM);
  u16* dst = bufA + ((size_t)e * CAP + p) * DDIM;
  #pragma unroll
  for (int j = 0; j < 4; j++) {
    float4 v = xr[j * 64 + l];
    uint2 u;
    u.x = (unsigned)f2bf(v.x) | ((unsigned)f2bf(v.y) << 16);
    u.y = (unsigned)f2bf(v.z) | ((unsigned)f2bf(v.w) << 16);
    *(uint2*)(dst + (size_t)(j * 64 + l) * 4) = u;
  }
}

// ---------------- expert GEMM: BM=256, BN=128, BK=64, 4 waves ----------------
// Counted-vmcnt pipeline (T4): B(t+1)'s 32 global loads are issued before the
// mid-iteration barrier and NOT drained (vmcnt(32) keeps them in flight through
// the MFMA phase). A staged via global_load_lds as before.
// EPI==1: h = gelu(A*W1 + b1) -> bf16   EPI==2: atomic gated combine of A*W2 + b2
template<int KTOT, int NTOT, int EPI>
__global__ __launch_bounds__(256, 2) void moe_gemm(
    const u16* __restrict__ Abuf, const float* __restrict__ W,
    const float* __restrict__ bias, u16* __restrict__ hout,
    float* __restrict__ out, const int* __restrict__ cnt,
    const int* __restrict__ s2a, const float* __restrict__ fg, int g0)
{
  constexpr int NCT = NTOT / 128;
  constexpr int NT  = KTOT / 64;
  int NB = gridDim.x;
  int b = blockIdx.x;
  int L = (b & 7) * (NB >> 3) + (b >> 3);   // XCD-bijective swizzle (NB % 8 == 0)
  int tcol = L % NCT;
  int rt   = (L / NCT) & 1;
  int el   = L / (NCT * 2);
  int e    = g0 + el;
  int cnte = cnt[e];
  int c0   = rt * 256;
  if (c0 >= cnte) return;
  int n0 = tcol * 128;

  int tid = threadIdx.x, l = tid & 63, w = tid >> 6;

  __shared__ char AsB[256 * 128];   // [256 rows][64 bf16] chunk-swizzled
  __shared__ char BsB[128 * 136];   // [128 n][64+4 bf16] K-major transposed

  const u16* Arows = Abuf + ((size_t)((EPI == 1 ? e : el)) * CAP + c0) * (size_t)KTOT;
  const float* We = W + (size_t)e * KTOT * NTOT;

  // per-thread B staging geometry: n = tid&127, k-group = tid>>7 (32 k each)
  int bn = tid & 127, bkg = tid >> 7;
  const float* Wt = We + (size_t)(bkg * 32) * NTOT + n0 + bn;
  char* BsW = BsB + bn * 136 + bkg * 64;

  float brB[32];
  #define LOADB(t) { \
    const float* p_ = Wt + (size_t)(t) * 64 * NTOT; \
    _Pragma("unroll") \
    for (int j_ = 0; j_ < 8; j_++) { \
      _Pragma("unroll") \
      for (int r_ = 0; r_ < 4; r_++) \
        brB[j_ * 4 + r_] = p_[(size_t)(j_ * 4 + r_) * NTOT]; \
    } }
  #define STOREB() { \
    _Pragma("unroll") \
    for (int j_ = 0; j_ < 8; j_++) { \
      uint2 u_; \
      u_.x = (unsigned)f2bf(brB[j_*4+0]) | ((unsigned)f2bf(brB[j_*4+1]) << 16); \
      u_.y = (unsigned)f2bf(brB[j_*4+2]) | ((unsigned)f2bf(brB[j_*4+3]) << 16); \
      *(uint2*)(BsW + j_ * 8) = u_; \
    } }

  f32x4 acc[4][8];
  #pragma unroll
  for (int m = 0; m < 4; m++)
    #pragma unroll
    for (int nn = 0; nn < 8; nn++)
      acc[m][nn] = (f32x4){0.f, 0.f, 0.f, 0.f};

  LOADB(0);   // prologue prefetch

  for (int t = 0; t < NT; ++t) {
    // --- stage A(t): 8 gl_lds per wave, source chunk-swizzled, LDS linear ---
    #pragma unroll
    for (int i = 0; i < 8; i++) {
      int r = i * 32 + w * 8 + (l >> 3);
      int cswz = (l & 7) ^ (r & 7);
      const char* gsrc = (const char*)(Arows + (size_t)r * KTOT + (size_t)t * 64) + cswz * 16;
      gl_lds16(gsrc, AsB + (i * 32 + w * 8) * 128);
    }
    // --- convert+store B(t): auto-wait drains B(t) regs only (A gl_lds younger) ---
    STOREB();
    __builtin_amdgcn_sched_barrier(0);
    // --- prefetch B(t+1): issue 32 loads, leave in flight across the barrier ---
    if (t + 1 < NT) {
      LOADB(t + 1);
      __builtin_amdgcn_sched_barrier(0);
      asm volatile("s_waitcnt vmcnt(32)" ::: "memory");   // A(t) done; B(t+1) in flight
    } else {
      asm volatile("s_waitcnt vmcnt(0)" ::: "memory");    // last iter: drain A(t)
    }
    asm volatile("s_waitcnt lgkmcnt(0)" ::: "memory");    // ds_writes visible
    __builtin_amdgcn_sched_barrier(0);
    __builtin_amdgcn_s_barrier();
    __builtin_amdgcn_sched_barrier(0);

    // --- MFMA phase ---
    #pragma unroll
    for (int k2 = 0; k2 < 2; k2++) {
      int kb = k2 * 32;
      s16x8 af[4], bf8[8];
      #pragma unroll
      for (int m = 0; m < 4; m++) {
        int R = w * 64 + m * 16 + (l & 15);
        int chunk = (kb >> 3) + (l >> 4);
        int sc = chunk ^ (R & 7);
        af[m] = *(const s16x8*)(AsB + R * 128 + sc * 16);
      }
      #pragma unroll
      for (int nn = 0; nn < 8; nn++) {
        int Nn = nn * 16 + (l & 15);
        int kk = kb + (l >> 4) * 8;
        const char* bp = BsB + Nn * 136 + kk * 2;
        union { s16x8 v8; s16x4 v4[2]; } bu;
        bu.v4[0] = *(const s16x4*)bp;
        bu.v4[1] = *(const s16x4*)(bp + 8);
        bf8[nn] = bu.v8;
      }
      #pragma unroll
      for (int m = 0; m < 4; m++)
        #pragma unroll
        for (int nn = 0; nn < 8; nn++)
          acc[m][nn] = __builtin_amdgcn_mfma_f32_16x16x32_bf16(af[m], bf8[nn], acc[m][nn], 0, 0, 0);
    }
    __builtin_amdgcn_s_barrier();
    __builtin_amdgcn_sched_barrier(0);
  }

  int lr = l >> 4, lc = l & 15;
  float bv[8];
  #pragma unroll
  for (int nn = 0; nn < 8; nn++) bv[nn] = bias[(size_t)e * NTOT + n0 + nn * 16 + lc];

  if (EPI == 1) {
    #pragma unroll
    for (int m = 0; m < 4; m++)
      #pragma unroll
      for (int q = 0; q < 4; q++) {
        int rowL = w * 64 + m * 16 + lr * 4 + q;
        if (c0 + rowL < cnte) {     // clip: rows >= cnte never read usefully
          #pragma unroll
          for (int nn = 0; nn < 8; nn++) {
            float vv = acc[m][nn][q] + bv[nn];
            vv = 0.5f * vv * (1.0f + erff(vv * 0.70710678118f));
            hout[(size_t)(el * CAP + c0 + rowL) * NTOT + (n0 + nn * 16 + lc)] = f2bf(vv);
          }
        }
      }
  } else {
    #pragma unroll
    for (int m = 0; m < 4; m++) {
      int rowbase = w * 64 + m * 16 + lr * 4;
      #pragma unroll
      for (int q = 0; q < 4; q++) {
        int slot = c0 + rowbase + q;
        if (slot < cnte) {
          int aidx = s2a[e * CAP + slot];
          int tok = aidx / 3;
          float gg = fg[aidx];
          #pragma unroll
          for (int nn = 0; nn < 8; nn++) {
            float vv = (acc[m][nn][q] + bv[nn]) * gg;
            atomicAdd(out + (size_t)tok * DDIM + (n0 + nn * 16 + lc), vv);
          }
        }
      }
    }
  }
}

extern "C" void kernel_launch(void* const* d_in, const int* in_sizes, int n_in,
                              void* d_out, int out_size, void* d_ws, size_t ws_size,
                              hipStream_t stream) {
  (void)in_sizes; (void)n_in; (void)ws_size;
  const float* x  = (const float*)d_in[0];
  const float* gw = (const float*)d_in[1];
  const float* gb = (const float*)d_in[2];
  const float* w1 = (const float*)d_in[3];
  const float* b1 = (const float*)d_in[4];
  const float* w2 = (const float*)d_in[5];
  const float* b2 = (const float*)d_in[6];
  float* out = (float*)d_out;

  char* ws = (char*)d_ws;
  int*   fe   = (int*)(ws);
  float* fg   = (float*)(ws + 49152);
  int*   posA = (int*)(ws + 98304);
  int*   s2a  = (int*)(ws + 147456);
  int*   cnt  = (int*)(ws + 278528);
  u16*   bufA = (u16*)(ws + (1 << 20));
  u16*   hbuf = (u16*)(ws + (1 << 20) + 67108864ull);

  zero_out<<<1024, 256, 0, stream>>>((float4*)out, out_size / 4);
  gate_topk<<<TTOK / 8, 512, 0, stream>>>(x, gw, gb, fe, fg);
  scan_pos<<<NEXP, 64, 0, stream>>>(fe, posA, s2a, cnt);
  dispatch<<<NASN, 64, 0, stream>>>(x, fe, posA, bufA);

  moe_gemm<DDIM, HDIM, 1><<<NEXP * 2 * (HDIM / 128), 256, 0, stream>>>(
      bufA, w1, b1, hbuf, nullptr, cnt, nullptr, nullptr, 0);
  moe_gemm<HDIM, DDIM, 2><<<NEXP * 2 * (DDIM / 128), 256, 0, stream>>>(
      hbuf, w2, b2, nullptr, out, cnt, s2a, fg, 0);
}